// Round 4
// baseline (654.789 us; speedup 1.0000x reference)
//
#include <hip/hip_runtime.h>
#include <hip/hip_bf16.h>

typedef unsigned short u16;
typedef unsigned int   u32;
typedef __attribute__((ext_vector_type(8))) short short8;
typedef __attribute__((ext_vector_type(4))) float f32x4;
typedef __attribute__((ext_vector_type(4))) u16   u16x4;

#define MFMA16(a,b,c) __builtin_amdgcn_mfma_f32_16x16x32_bf16((a),(b),(c),0,0,0)

#define BATCH 4
#define NPIX  4096     // 64*64
#define CCH   512
#define DDIM  64

static __device__ __forceinline__ u16 f2bf(float f){
  __hip_bfloat16 h = __float2bfloat16(f);
  return __builtin_bit_cast(u16, h);
}
static __device__ __forceinline__ float bf2f(u16 u){
  __hip_bfloat16 h = __builtin_bit_cast(__hip_bfloat16, u);
  return __bfloat162float(h);
}

// ---------------- kernel 1: convert x and Wv to bf16 ----------------
__global__ __launch_bounds__(256) void k_convert(const f32x4* __restrict__ x,
                                                 const f32x4* __restrict__ wv,
                                                 u16x4* __restrict__ xhi,
                                                 u16x4* __restrict__ wvb){
  const int n1 = (BATCH*NPIX*CCH)/4;   // x in float4s
  const int n2 = (CCH*CCH)/4;          // Wv in float4s
  for (int i = blockIdx.x*blockDim.x + threadIdx.x; i < n1+n2; i += gridDim.x*blockDim.x){
    f32x4 v = (i < n1) ? x[i] : wv[i-n1];
    u16x4 o;
    o[0]=f2bf(v[0]); o[1]=f2bf(v[1]); o[2]=f2bf(v[2]); o[3]=f2bf(v[3]);
    if (i < n1) xhi[i] = o; else wvb[i-n1] = o;
  }
}

// ---------------- kernel 2: q,k projection (fp32) + hi/lo split ----------------
__global__ __launch_bounds__(256) void k_qkproj(const float* __restrict__ x,
                                                const float* __restrict__ Wq,
                                                const float* __restrict__ Wk,
                                                u16* __restrict__ qhi, u16* __restrict__ qlo,
                                                u16* __restrict__ khi, u16* __restrict__ klo){
  __shared__ float xs[32][512];    // 64 KB
  const int pix0 = blockIdx.x * 32;
  {
    const f32x4* xg = (const f32x4*)(x + (size_t)pix0*CCH);
    f32x4* xsv = (f32x4*)(&xs[0][0]);
    #pragma unroll
    for (int it=0; it<16; ++it) xsv[threadIdx.x + it*256] = xg[threadIdx.x + it*256];
  }
  __syncthreads();
  const int col = threadIdx.x & 127;   // 0..63 -> q, 64..127 -> k  (wave-uniform)
  const int grp = threadIdx.x >> 7;    // pixel half
  const float* W = (col < 64) ? Wq : Wk;
  const int wc = col & 63;
  float acc[16];
  #pragma unroll
  for (int p=0;p<16;++p) acc[p] = 0.f;
  #pragma unroll 2
  for (int c=0;c<512;c+=4){
    float w0 = W[(c+0)*64 + wc];
    float w1 = W[(c+1)*64 + wc];
    float w2 = W[(c+2)*64 + wc];
    float w3 = W[(c+3)*64 + wc];
    #pragma unroll
    for (int p=0;p<16;++p){
      f32x4 xv = *(const f32x4*)(&xs[grp*16+p][c]);
      acc[p] += xv[0]*w0 + xv[1]*w1 + xv[2]*w2 + xv[3]*w3;
    }
  }
  #pragma unroll
  for (int p=0;p<16;++p){
    int pix = pix0 + grp*16 + p;
    float v = acc[p];
    u16 hi = f2bf(v);
    u16 lo = f2bf(v - bf2f(hi));
    if (col < 64){ qhi[pix*64+wc] = hi; qlo[pix*64+wc] = lo; }
    else         { khi[pix*64+wc] = hi; klo[pix*64+wc] = lo; }
  }
}

// ---------------- kernel 3: v projection (bf16 MFMA), writes V^T ----------------
// V^T layout: [BATCH][CCH][NPIX] bf16
__global__ __launch_bounds__(256) void k_vproj(const u16* __restrict__ xhi,
                                               const u16* __restrict__ wvb,
                                               u16* __restrict__ vT){
  __shared__ u16 As[64][72];      // x tile [pix][k], padded
  __shared__ u16 Bs[64][266];     // Wv tile [k][c], padded
  const int pix0 = blockIdx.x * 64;
  const int c0   = blockIdx.y * 256;
  const int tid = threadIdx.x;
  const int w = tid >> 6, l = tid & 63;
  const int lg = l >> 4, ll = l & 15;
  f32x4 acc[4][4];
  #pragma unroll
  for (int mf=0;mf<4;++mf)
    #pragma unroll
    for (int nf=0;nf<4;++nf){ f32x4 z = {0.f,0.f,0.f,0.f}; acc[mf][nf] = z; }

  for (int ks=0; ks<8; ++ks){
    __syncthreads();
    #pragma unroll
    for (int it=0; it<2; ++it){
      int ch = tid + it*256; int r = ch>>3, c8 = ch&7;
      *(uint4*)(&As[r][c8*8]) = *(const uint4*)(&xhi[(size_t)(pix0+r)*CCH + ks*64 + c8*8]);
    }
    #pragma unroll
    for (int it=0; it<8; ++it){
      int ch = tid + it*256; int r = ch>>5, c32 = ch&31;
      uint4 d = *(const uint4*)(&wvb[(size_t)(ks*64+r)*CCH + c0 + c32*8]);
      u32* dst = (u32*)(&Bs[r][c32*8]);
      dst[0]=d.x; dst[1]=d.y; dst[2]=d.z; dst[3]=d.w;
    }
    __syncthreads();
    #pragma unroll
    for (int kc=0;kc<2;++kc){
      short8 a[4];
      #pragma unroll
      for (int mf=0;mf<4;++mf) a[mf] = *(const short8*)(&As[mf*16 + ll][kc*32 + lg*8]);
      #pragma unroll
      for (int nf=0;nf<4;++nf){
        short8 bb;
        int cc = w*64 + nf*16 + ll;
        #pragma unroll
        for (int e=0;e<8;++e) bb[e] = (short)Bs[kc*32 + lg*8 + e][cc];
        #pragma unroll
        for (int mf=0;mf<4;++mf) acc[mf][nf] = MFMA16(a[mf], bb, acc[mf][nf]);
      }
    }
  }
  #pragma unroll
  for (int mf=0;mf<4;++mf){
    #pragma unroll
    for (int nf=0;nf<4;++nf){
      int pix = pix0 + mf*16 + lg*4;
      int c   = c0 + w*64 + nf*16 + ll;
      u16x4 o;
      #pragma unroll
      for (int r=0;r<4;++r) o[r] = f2bf(acc[mf][nf][r]);
      size_t off = ((size_t)((pix>>12)*CCH + c))*NPIX + (pix & 4095);
      *(u16x4*)(vT + off) = o;
    }
  }
}

// ---------------- kernel 4 v3: flash attention, csplit=4, 16 waves/CU ----------
// 1D grid 1024: id = itile*16 + pair, pair = cq*4 + b  (XCD locality: all blocks
// of one (cq,b) share an XCD-residue mod 8; pairs p,p+8 share batch).
// Block: 64 i-rows x 128 out-cols, 4 waves. Wave wv: softmax rows
// [i0+wv*16,+16), PV cols [c0+wv*32,+32) x all 64 i. One barrier per j-tile.
__global__ __launch_bounds__(256,4) void k_flash3(const u16* __restrict__ qhi, const u16* __restrict__ qlo,
                                                  const u16* __restrict__ khi, const u16* __restrict__ klo,
                                                  const u16* __restrict__ vT,
                                                  const float* __restrict__ gamma_p,
                                                  float* __restrict__ out){
  __shared__ u16  Ps[2][64][72];     // P tile, [i][j] padded, double-buffered
  __shared__ float scl_s[2][64];     // per-row rescale factor
  __shared__ float l_s[64];          // final denominators
  const int id   = blockIdx.x;
  const int pair = id & 15;
  const int i0   = (id >> 4) * 64;
  const int cq   = pair >> 2;
  const int b    = pair & 3;
  const int c0   = cq * 128;
  const int tid = threadIdx.x;
  const int wv = tid >> 6, l = tid & 63;
  const int lg = l >> 4, ll = l & 15;

  // K B-fragments for this wave's 16 i-rows (hi+lo), kept in regs
  short8 kh[2], kl[2];
  #pragma unroll
  for (int kc=0;kc<2;++kc){
    size_t a = ((size_t)(b*NPIX + i0 + wv*16 + ll))*DDIM + kc*32 + lg*8;
    kh[kc] = *(const short8*)(khi + a);
    kl[kc] = *(const short8*)(klo + a);
  }

  f32x4 acc[4][2];
  #pragma unroll
  for (int mf=0;mf<4;++mf)
    #pragma unroll
    for (int nf=0;nf<2;++nf){ f32x4 z = {0.f,0.f,0.f,0.f}; acc[mf][nf] = z; }
  float m_run = -1e30f, l_run = 0.f;   // for i-row = wv*16+ll (replicated over lg)

  const u16* vbase = vT  + (size_t)b*CCH*NPIX;
  const u16* qh_b  = qhi + (size_t)b*NPIX*DDIM;
  const u16* ql_b  = qlo + (size_t)b*NPIX*DDIM;

  for (int jt=0; jt<64; ++jt){
    const int j0 = jt*64, buf = jt & 1;

    // ---- prefetch this tile's V fragments FIRST (no deps -> stay in flight) ----
    short8 vb[4];
    #pragma unroll
    for (int kc=0;kc<2;++kc)
      #pragma unroll
      for (int nf=0;nf<2;++nf){
        int c = c0 + wv*32 + nf*16 + ll;
        vb[kc*2+nf] = *(const short8*)(vbase + (size_t)c*NPIX + j0 + kc*32 + lg*8);
      }

    // ---- S^T = Q . K^T for this wave's 16 i, all 64 j (3-term hi/lo) ----
    f32x4 s[4];
    #pragma unroll
    for (int jf=0;jf<4;++jf){ f32x4 z = {0.f,0.f,0.f,0.f}; s[jf] = z; }
    #pragma unroll
    for (int kc=0;kc<2;++kc){
      #pragma unroll
      for (int jf=0;jf<4;++jf){
        size_t qa = (size_t)(j0 + jf*16 + ll)*DDIM + kc*32 + lg*8;
        short8 qh = *(const short8*)(qh_b + qa);
        short8 ql = *(const short8*)(ql_b + qa);
        s[jf] = MFMA16(qh, kh[kc], s[jf]);
        s[jf] = MFMA16(ql, kh[kc], s[jf]);
        s[jf] = MFMA16(qh, kl[kc], s[jf]);
      }
    }

    // ---- in-lane softmax over 16 j-values + reduce over 4 lane-groups ----
    float mx = fmaxf(fmaxf(fmaxf(s[0][0],s[0][1]),fmaxf(s[0][2],s[0][3])),
                     fmaxf(fmaxf(s[1][0],s[1][1]),fmaxf(s[1][2],s[1][3])));
    mx = fmaxf(mx, fmaxf(fmaxf(fmaxf(s[2][0],s[2][1]),fmaxf(s[2][2],s[2][3])),
                         fmaxf(fmaxf(s[3][0],s[3][1]),fmaxf(s[3][2],s[3][3]))));
    mx = fmaxf(mx, __shfl_xor(mx, 16));
    mx = fmaxf(mx, __shfl_xor(mx, 32));
    float mnew = fmaxf(m_run, mx);
    float sc = __expf(m_run - mnew);
    float psum = 0.f;
    #pragma unroll
    for (int jf=0;jf<4;++jf)
      #pragma unroll
      for (int r=0;r<4;++r){
        float v = __expf(s[jf][r] - mnew);
        s[jf][r] = v; psum += v;
      }
    psum += __shfl_xor(psum, 16);
    psum += __shfl_xor(psum, 32);
    l_run = l_run*sc + psum;
    m_run = mnew;

    // ---- stage P (bf16) + scl ----
    #pragma unroll
    for (int jf=0;jf<4;++jf){
      u16x4 pk;
      #pragma unroll
      for (int r=0;r<4;++r) pk[r] = f2bf(s[jf][r]);
      *(u16x4*)(&Ps[buf][wv*16 + ll][jf*16 + lg*4]) = pk;
    }
    if (lg == 0) scl_s[buf][wv*16 + ll] = sc;
    __syncthreads();

    // ---- rescale acc (usually skipped once running max settles) ----
    f32x4 sc4[4];
    #pragma unroll
    for (int mf=0;mf<4;++mf) sc4[mf] = *(const f32x4*)(&scl_s[buf][mf*16 + lg*4]);
    bool need = false;
    #pragma unroll
    for (int mf=0;mf<4;++mf)
      #pragma unroll
      for (int r=0;r<4;++r) need |= (sc4[mf][r] != 1.0f);
    if (__any(need)){
      #pragma unroll
      for (int mf=0;mf<4;++mf)
        #pragma unroll
        for (int nf=0;nf<2;++nf)
          #pragma unroll
          for (int r=0;r<4;++r) acc[mf][nf][r] *= sc4[mf][r];
    }

    // ---- PV: A = P (all 64 i) from LDS, B = prefetched V ----
    #pragma unroll
    for (int kc=0;kc<2;++kc){
      short8 pa[4];
      #pragma unroll
      for (int mf=0;mf<4;++mf) pa[mf] = *(const short8*)(&Ps[buf][mf*16 + ll][kc*32 + lg*8]);
      #pragma unroll
      for (int nf=0;nf<2;++nf)
        #pragma unroll
        for (int mf=0;mf<4;++mf) acc[mf][nf] = MFMA16(pa[mf], vb[kc*2+nf], acc[mf][nf]);
    }
  }

  // ---- epilogue ----
  if (lg == 0) l_s[wv*16 + ll] = l_run;
  __syncthreads();
  const float g = gamma_p[0];
  #pragma unroll
  for (int mf=0;mf<4;++mf){
    f32x4 lv = *(const f32x4*)(&l_s[mf*16 + lg*4]);
    f32x4 inv;
    #pragma unroll
    for (int r=0;r<4;++r) inv[r] = g / lv[r];
    #pragma unroll
    for (int nf=0;nf<2;++nf){
      #pragma unroll
      for (int r=0;r<4;++r){
        int row = mf*16 + lg*4 + r;
        int c   = c0 + wv*32 + nf*16 + ll;
        out[((size_t)(b*NPIX + i0 + row))*CCH + c] = acc[mf][nf][r] * inv[r];
      }
    }
  }
}

extern "C" void kernel_launch(void* const* d_in, const int* in_sizes, int n_in,
                              void* d_out, int out_size, void* d_ws, size_t ws_size,
                              hipStream_t stream) {
  (void)in_sizes; (void)n_in; (void)out_size; (void)ws_size;
  const float* x  = (const float*)d_in[0];
  const float* Wq = (const float*)d_in[1];
  const float* Wk = (const float*)d_in[2];
  const float* Wv = (const float*)d_in[3];
  const float* gm = (const float*)d_in[4];
  float* out = (float*)d_out;

  // persistent scratch in d_ws (24 MB needed)
  u16* qhi = (u16*)d_ws;
  u16* qlo = qhi + (size_t)BATCH*NPIX*DDIM;
  u16* khi = qlo + (size_t)BATCH*NPIX*DDIM;
  u16* klo = khi + (size_t)BATCH*NPIX*DDIM;
  u16* vT  = klo + (size_t)BATCH*NPIX*DDIM;        // [B][C][N], 16 MB

  // transient bf16 copies inside d_out (consumed by k_vproj before k_flash3 writes)
  u16* xhi = (u16*)d_out;                          // 16 MB
  u16* wvb = xhi + (size_t)BATCH*NPIX*CCH;         // 0.5 MB

  k_convert<<<dim3(2048), dim3(256), 0, stream>>>((const f32x4*)x, (const f32x4*)Wv,
                                                  (u16x4*)xhi, (u16x4*)wvb);
  k_qkproj<<<dim3(512), dim3(256), 0, stream>>>(x, Wq, Wk, qhi, qlo, khi, klo);
  k_vproj<<<dim3(256,2), dim3(256), 0, stream>>>(xhi, wvb, vT);
  k_flash3<<<dim3(1024), dim3(256), 0, stream>>>(qhi, qlo, khi, klo, vT, gm, out);
}